// Round 1
// baseline (20387.569 us; speedup 1.0000x reference)
//
#include <hip/hip_runtime.h>
#include <hip/hip_bf16.h>

// ---------------------------------------------------------------------------
// 3-layer original-paper GRU, B=128, T=128, I=512, H={512,1024,2048}.
// Strategy (round 1 baseline):
//   - bf16 MFMA GEMMs (fp32 accum), fp32 hidden state, fp32 gate math.
//   - t-major scan; per (t, layer): two GEMM kernels
//       zr: [x|h] @ [Wih_zr|Whh_zr]^T + b_zr -> z (f32), r*h (bf16)
//       n : x@Wn_ih^T + (r*h)@Wn_hh^T + b_n -> tanh -> h', out += mask*h'
//   - GEMM tile 64x64, BK=64, 256 thr (4 waves x 32x32), global_load_lds x16.
// Workspace: bf16 x + bf16 weights + h (f32+bf16) + z + rh  (~71 MB).
// ---------------------------------------------------------------------------

typedef __attribute__((ext_vector_type(8))) short s16x8;
typedef __attribute__((ext_vector_type(4))) float f32x4;

#define LLDS16(g, s)                                                          \
  __builtin_amdgcn_global_load_lds(                                           \
      (const __attribute__((address_space(1))) void*)(g),                     \
      (__attribute__((address_space(3))) void*)(s), 16, 0, 0)

__device__ __forceinline__ unsigned short f2b(float f) {
  // round-to-nearest-even f32 -> bf16 (finite inputs only)
  unsigned int u = __float_as_uint(f);
  unsigned int r = (u + 0x7FFFu + ((u >> 16) & 1u)) >> 16;
  return (unsigned short)r;
}

__device__ __forceinline__ float sigmoidf_(float x) {
  return 1.0f / (1.0f + __expf(-x));
}

__device__ __forceinline__ float tanhf_(float x) {
  x = fminf(fmaxf(x, -15.0f), 15.0f);
  float e = __expf(-2.0f * x);
  return (1.0f - e) / (1.0f + e);
}

// Accumulate C[64x64 tile] += A[M,K] @ B[N,K]^T over one operand pair.
// A row-major (ldA elems), B row-major [N,K] (ldB elems). K % 64 == 0.
// As/Bs: 4096-ushort LDS tiles. acc: 2x2 mfma 16x16 frags per wave.
__device__ __forceinline__ void gemm_phase(
    const unsigned short* __restrict__ A, size_t ldA,
    const unsigned short* __restrict__ B, size_t ldB, int K,
    int bm, int bn, unsigned short* As, unsigned short* Bs, f32x4 acc[2][2]) {
  const int tid = threadIdx.x;
  const int wave = tid >> 6, lane = tid & 63;
  const int wm = wave >> 1, wn = wave & 1;
  const int quad = lane >> 4, l16 = lane & 15;
  const int srow_in_chunk = lane >> 3;       // 0..7
  const int scol = (lane & 7) * 8;           // element col of 16B chunk

  for (int k0 = 0; k0 < K; k0 += 64) {
    __syncthreads();  // previous iter's LDS reads done before overwrite
#pragma unroll
    for (int i = 0; i < 2; ++i) {
      int c = wave * 2 + i;                  // chunk 0..7 (8 rows each)
      int row = c * 8 + srow_in_chunk;       // 0..63
      LLDS16(A + (size_t)(bm * 64 + row) * ldA + k0 + scol, As + c * 512);
      LLDS16(B + (size_t)(bn * 64 + row) * ldB + k0 + scol, Bs + c * 512);
    }
    __syncthreads();  // drains vmcnt for global_load_lds
#pragma unroll
    for (int ks = 0; ks < 2; ++ks) {
      s16x8 av[2], bv[2];
#pragma unroll
      for (int mi = 0; mi < 2; ++mi)
        av[mi] = *(const s16x8*)(As + (size_t)(wm * 32 + mi * 16 + l16) * 64 +
                                 ks * 32 + quad * 8);
#pragma unroll
      for (int ni = 0; ni < 2; ++ni)
        bv[ni] = *(const s16x8*)(Bs + (size_t)(wn * 32 + ni * 16 + l16) * 64 +
                                 ks * 32 + quad * 8);
#pragma unroll
      for (int mi = 0; mi < 2; ++mi)
#pragma unroll
        for (int ni = 0; ni < 2; ++ni)
          acc[mi][ni] = __builtin_amdgcn_mfma_f32_16x16x32_bf16(
              av[mi], bv[ni], acc[mi][ni], 0, 0, 0);
    }
  }
}

// z/r gates: C[128, 2H] = A1@B1^T + A2@B2^T + bias. cols [0,H)=z, [H,2H)=r.
__global__ __launch_bounds__(256) void step_zr_kernel(
    const unsigned short* __restrict__ A1, int ldA1, int K1,
    const unsigned short* __restrict__ A2, int K2,
    const unsigned short* __restrict__ B1, const unsigned short* __restrict__ B2,
    const float* __restrict__ bias, const float* __restrict__ hf,
    float* __restrict__ zbuf, unsigned short* __restrict__ rh, int H) {
  __shared__ unsigned short As[4096], Bs[4096];
  f32x4 acc[2][2] = {};
  const int bm = blockIdx.x, bn = blockIdx.y;
  gemm_phase(A1, (size_t)ldA1, B1, (size_t)K1, K1, bm, bn, As, Bs, acc);
  gemm_phase(A2, (size_t)K2, B2, (size_t)K2, K2, bm, bn, As, Bs, acc);

  const int tid = threadIdx.x, wave = tid >> 6, lane = tid & 63;
  const int wm = wave >> 1, wn = wave & 1, quad = lane >> 4, l16 = lane & 15;
#pragma unroll
  for (int mi = 0; mi < 2; ++mi)
#pragma unroll
    for (int ni = 0; ni < 2; ++ni) {
      int col = bn * 64 + wn * 32 + ni * 16 + l16;
      float bv = bias[col];
#pragma unroll
      for (int r = 0; r < 4; ++r) {
        int row = bm * 64 + wm * 32 + mi * 16 + quad * 4 + r;
        float v = acc[mi][ni][r] + bv;
        if (col < H) {  // H%64==0 -> uniform per block
          zbuf[(size_t)row * H + col] = sigmoidf_(v);
        } else {
          int j = col - H;
          float rr = sigmoidf_(v);
          rh[(size_t)row * H + j] = f2b(rr * hf[(size_t)row * H + j]);
        }
      }
    }
}

// n gate + h update + masked output accumulation.
__global__ __launch_bounds__(256) void step_n_kernel(
    const unsigned short* __restrict__ A1, int ldA1, int K1,
    const unsigned short* __restrict__ RH, int K2,
    const unsigned short* __restrict__ B1, const unsigned short* __restrict__ B2,
    const float* __restrict__ biasn, const float* __restrict__ zbuf,
    float* __restrict__ hf, unsigned short* __restrict__ hb,
    float* __restrict__ out, int out_off, const float* __restrict__ mask,
    int t, int H) {
  __shared__ unsigned short As[4096], Bs[4096];
  f32x4 acc[2][2] = {};
  const int bm = blockIdx.x, bn = blockIdx.y;
  gemm_phase(A1, (size_t)ldA1, B1, (size_t)K1, K1, bm, bn, As, Bs, acc);
  gemm_phase(RH, (size_t)K2, B2, (size_t)K2, K2, bm, bn, As, Bs, acc);

  const int tid = threadIdx.x, wave = tid >> 6, lane = tid & 63;
  const int wm = wave >> 1, wn = wave & 1, quad = lane >> 4, l16 = lane & 15;
#pragma unroll
  for (int mi = 0; mi < 2; ++mi)
#pragma unroll
    for (int ni = 0; ni < 2; ++ni) {
      int col = bn * 64 + wn * 32 + ni * 16 + l16;
      float bv = biasn[col];
#pragma unroll
      for (int r = 0; r < 4; ++r) {
        int row = bm * 64 + wm * 32 + mi * 16 + quad * 4 + r;
        float v = acc[mi][ni][r] + bv;
        float nv = tanhf_(v);
        size_t idx = (size_t)row * H + col;
        float z = zbuf[idx];
        float hp = hf[idx];
        float hn = (1.0f - z) * nv + z * hp;
        hf[idx] = hn;
        hb[idx] = f2b(hn);
        out[(size_t)row * 3584 + out_off + col] += mask[row * 128 + t] * hn;
      }
    }
}

__global__ void cast_kernel(const float* __restrict__ src,
                            unsigned short* __restrict__ dst, int n) {
  int i = blockIdx.x * 256 + threadIdx.x;
  if (i < n) dst[i] = f2b(src[i]);
}

extern "C" void kernel_launch(void* const* d_in, const int* in_sizes, int n_in,
                              void* d_out, int out_size, void* d_ws,
                              size_t ws_size, hipStream_t stream) {
  const int B = 128, T = 128, I = 512;
  const int Hs[3] = {512, 1024, 2048};
  const int outoff[3] = {0, 512, 1536};

  const float* x = (const float*)d_in[0];
  const float* mask = (const float*)d_in[1];
  const float* Wih[3] = {(const float*)d_in[2], (const float*)d_in[5],
                         (const float*)d_in[8]};
  const float* Whh[3] = {(const float*)d_in[3], (const float*)d_in[6],
                         (const float*)d_in[9]};
  const float* bias[3] = {(const float*)d_in[4], (const float*)d_in[7],
                          (const float*)d_in[10]};

  char* ws = (char*)d_ws;
  size_t off = 0;
  auto alloc = [&](size_t bytes) -> void* {
    void* p = ws + off;
    off = (off + bytes + 255) & ~(size_t)255;
    return p;
  };

  unsigned short* xb = (unsigned short*)alloc((size_t)B * T * I * 2);
  unsigned short *wihb[3], *whhb[3];
  for (int l = 0; l < 3; ++l) {
    int inl = (l == 0) ? I : Hs[l - 1];
    wihb[l] = (unsigned short*)alloc((size_t)3 * Hs[l] * inl * 2);
  }
  for (int l = 0; l < 3; ++l)
    whhb[l] = (unsigned short*)alloc((size_t)3 * Hs[l] * Hs[l] * 2);
  size_t hstart = off;
  float* hf[3];
  unsigned short* hb[3];
  for (int l = 0; l < 3; ++l) hf[l] = (float*)alloc((size_t)B * Hs[l] * 4);
  for (int l = 0; l < 3; ++l)
    hb[l] = (unsigned short*)alloc((size_t)B * Hs[l] * 2);
  size_t hend = off;
  float* zbuf = (float*)alloc((size_t)B * 2048 * 4);
  unsigned short* rh = (unsigned short*)alloc((size_t)B * 2048 * 2);
  (void)ws_size;

  // --- prep: bf16 casts, zero h and out ---
  auto cast = [&](const float* s, unsigned short* d, int n) {
    cast_kernel<<<(n + 255) / 256, 256, 0, stream>>>(s, d, n);
  };
  cast(x, xb, B * T * I);
  for (int l = 0; l < 3; ++l) {
    int inl = (l == 0) ? I : Hs[l - 1];
    cast(Wih[l], wihb[l], 3 * Hs[l] * inl);
    cast(Whh[l], whhb[l], 3 * Hs[l] * Hs[l]);
  }
  hipMemsetAsync(ws + hstart, 0, hend - hstart, stream);
  hipMemsetAsync(d_out, 0, (size_t)out_size * 4, stream);

  // --- scan ---
  for (int t = 0; t < T; ++t) {
    for (int l = 0; l < 3; ++l) {
      int H = Hs[l];
      int inl = (l == 0) ? I : Hs[l - 1];
      const unsigned short* A1 = (l == 0) ? xb + (size_t)t * I : hb[l - 1];
      int ldA1 = (l == 0) ? T * I : inl;

      dim3 gzr(2, (unsigned)(2 * H / 64));
      step_zr_kernel<<<gzr, 256, 0, stream>>>(A1, ldA1, inl, hb[l], H, wihb[l],
                                              whhb[l], bias[l], hf[l], zbuf,
                                              rh, H);
      dim3 gn(2, (unsigned)(H / 64));
      step_n_kernel<<<gn, 256, 0, stream>>>(
          A1, ldA1, inl, rh, H, wihb[l] + (size_t)2 * H * inl,
          whhb[l] + (size_t)2 * H * H, bias[l] + 2 * H, zbuf, hf[l], hb[l],
          (float*)d_out, outoff[l], mask, t, H);
    }
  }
}

// Round 2
// 14354.909 us; speedup vs baseline: 1.4203x; 1.4203x over previous
//
#include <hip/hip_runtime.h>
#include <hip/hip_bf16.h>

// ---------------------------------------------------------------------------
// 3-layer original-paper GRU, B=128, T=128, I=512, H={512,1024,2048}.
// Round 2: new GEMM core.
//   - BK=128 chunks, LDS double-buffered, prefetch issued AFTER the barrier so
//     chunk c+1's global_load_lds overlaps chunk c's MFMA (1 barrier/chunk).
//   - XOR-swizzled LDS layout (cg ^ (row&15)) applied via the global-read lane
//     mapping (global_load_lds is wave-uniform-base + lane*16B): fragment
//     ds_read_b128 becomes conflict-free (2-way max), global reads stay
//     coalesced (permutation within each 256B row segment).
//   - Two operand pairs (input phase + hidden phase) fused into one virtual
//     chunk stream so the pipeline stays full across the seam.
// Structure otherwise as round 1: per (t,layer) two kernels (zr, n).
// ---------------------------------------------------------------------------

typedef __attribute__((ext_vector_type(8))) short s16x8;
typedef __attribute__((ext_vector_type(4))) float f32x4;

#define LLDS16(g, s)                                                          \
  __builtin_amdgcn_global_load_lds(                                           \
      (const __attribute__((address_space(1))) void*)(g),                     \
      (__attribute__((address_space(3))) void*)(s), 16, 0, 0)

__device__ __forceinline__ unsigned short f2b(float f) {
  unsigned int u = __float_as_uint(f);
  unsigned int r = (u + 0x7FFFu + ((u >> 16) & 1u)) >> 16;
  return (unsigned short)r;
}

__device__ __forceinline__ float sigmoidf_(float x) {
  return 1.0f / (1.0f + __expf(-x));
}

__device__ __forceinline__ float tanhf_(float x) {
  x = fminf(fmaxf(x, -15.0f), 15.0f);
  float e = __expf(-2.0f * x);
  return (1.0f - e) / (1.0f + e);
}

// Stage one 64x128 bf16 tile into LDS (16 KB), XOR-swizzled.
// LDS addr of (r, cg) = r*256B + ((cg ^ (r&15)))*16B.  4 issues/thread.
__device__ __forceinline__ void issue_tile(const unsigned short* __restrict__ g,
                                           size_t ld, int rowbase, int k0,
                                           unsigned short* lds) {
  const int tid = threadIdx.x;
  const int wave = tid >> 6, lane = tid & 63;
#pragma unroll
  for (int j = 0; j < 4; ++j) {
    int s = wave * 4 + j;             // segment: 4 rows of 256B = 1KB
    int r = s * 4 + (lane >> 4);      // tile row 0..63
    int cg = (lane & 15) ^ (r & 15);  // swizzled 16B column group
    LLDS16(g + (size_t)(rowbase + r) * ld + k0 + cg * 8, lds + s * 512);
  }
}

// One BK=128 chunk of MFMA from swizzled LDS tiles.
__device__ __forceinline__ void compute_chunk(const unsigned short* Ab,
                                              const unsigned short* Bb,
                                              f32x4 acc[2][2]) {
  const int tid = threadIdx.x;
  const int wave = tid >> 6, lane = tid & 63;
  const int wm = wave >> 1, wn = wave & 1, quad = lane >> 4, l16 = lane & 15;
#pragma unroll
  for (int ks = 0; ks < 4; ++ks) {
    s16x8 av[2], bv[2];
#pragma unroll
    for (int mi = 0; mi < 2; ++mi) {
      int r = wm * 32 + mi * 16 + l16;
      av[mi] = *(const s16x8*)(Ab + (size_t)r * 128 +
                               (((ks * 4 + quad) ^ (r & 15)) * 8));
    }
#pragma unroll
    for (int ni = 0; ni < 2; ++ni) {
      int r = wn * 32 + ni * 16 + l16;
      bv[ni] = *(const s16x8*)(Bb + (size_t)r * 128 +
                               (((ks * 4 + quad) ^ (r & 15)) * 8));
    }
#pragma unroll
    for (int mi = 0; mi < 2; ++mi)
#pragma unroll
      for (int ni = 0; ni < 2; ++ni)
        acc[mi][ni] = __builtin_amdgcn_mfma_f32_16x16x32_bf16(
            av[mi], bv[ni], acc[mi][ni], 0, 0, 0);
  }
}

// acc += A1@B1^T (K1) + A2@B2^T (K2); B row-major [N,K]. K1,K2 % 128 == 0.
__device__ __forceinline__ void gemm2(
    const unsigned short* __restrict__ A1, size_t ldA1, int K1,
    const unsigned short* __restrict__ A2, size_t ldA2, int K2,
    const unsigned short* __restrict__ B1, size_t ldB1,
    const unsigned short* __restrict__ B2, size_t ldB2, int bm, int bn,
    unsigned short* As, unsigned short* Bs, f32x4 acc[2][2]) {
  const int n1 = K1 >> 7;
  const int total = n1 + (K2 >> 7);
  auto issue = [&](int c, int buf) {
    const unsigned short *A, *B;
    size_t lA, lB;
    int k0;
    if (c < n1) {
      A = A1; B = B1; lA = ldA1; lB = ldB1; k0 = c << 7;
    } else {
      A = A2; B = B2; lA = ldA2; lB = ldB2; k0 = (c - n1) << 7;
    }
    issue_tile(A, lA, bm * 64, k0, As + buf * 8192);
    issue_tile(B, lB, bn * 64, k0, Bs + buf * 8192);
  };
  issue(0, 0);
  for (int c = 0; c < total; ++c) {
    __syncthreads();  // drains vmcnt(0): chunk c resident; also WAR-protects
    if (c + 1 < total) issue(c + 1, (c + 1) & 1);
    compute_chunk(As + (c & 1) * 8192, Bs + (c & 1) * 8192, acc);
  }
}

// z/r gates: C[128, 2H] = A1@B1^T + h@B2^T + bias. cols [0,H)=z, [H,2H)=r.
__global__ __launch_bounds__(256) void step_zr_kernel(
    const unsigned short* __restrict__ A1, int ldA1, int K1,
    const unsigned short* __restrict__ A2, int K2,
    const unsigned short* __restrict__ B1, const unsigned short* __restrict__ B2,
    const float* __restrict__ bias, const float* __restrict__ hf,
    float* __restrict__ zbuf, unsigned short* __restrict__ rh, int H) {
  __shared__ unsigned short As[2 * 8192], Bs[2 * 8192];
  f32x4 acc[2][2] = {};
  const int bm = blockIdx.x, bn = blockIdx.y;
  gemm2(A1, (size_t)ldA1, K1, A2, (size_t)K2, K2, B1, (size_t)K1, B2,
        (size_t)K2, bm, bn, As, Bs, acc);

  const int tid = threadIdx.x, wave = tid >> 6, lane = tid & 63;
  const int wm = wave >> 1, wn = wave & 1, quad = lane >> 4, l16 = lane & 15;
#pragma unroll
  for (int mi = 0; mi < 2; ++mi)
#pragma unroll
    for (int ni = 0; ni < 2; ++ni) {
      int col = bn * 64 + wn * 32 + ni * 16 + l16;
      float bv = bias[col];
#pragma unroll
      for (int r = 0; r < 4; ++r) {
        int row = bm * 64 + wm * 32 + mi * 16 + quad * 4 + r;
        float v = acc[mi][ni][r] + bv;
        if (col < H) {  // H%64==0 -> uniform per block
          zbuf[(size_t)row * H + col] = sigmoidf_(v);
        } else {
          int j = col - H;
          float rr = sigmoidf_(v);
          rh[(size_t)row * H + j] = f2b(rr * hf[(size_t)row * H + j]);
        }
      }
    }
}

// n gate + h update + masked output accumulation.
__global__ __launch_bounds__(256) void step_n_kernel(
    const unsigned short* __restrict__ A1, int ldA1, int K1,
    const unsigned short* __restrict__ RH, int K2,
    const unsigned short* __restrict__ B1, const unsigned short* __restrict__ B2,
    const float* __restrict__ biasn, const float* __restrict__ zbuf,
    float* __restrict__ hf, unsigned short* __restrict__ hb,
    float* __restrict__ out, int out_off, const float* __restrict__ mask,
    int t, int H) {
  __shared__ unsigned short As[2 * 8192], Bs[2 * 8192];
  f32x4 acc[2][2] = {};
  const int bm = blockIdx.x, bn = blockIdx.y;
  gemm2(A1, (size_t)ldA1, K1, RH, (size_t)K2, K2, B1, (size_t)K1, B2,
        (size_t)K2, bm, bn, As, Bs, acc);

  const int tid = threadIdx.x, wave = tid >> 6, lane = tid & 63;
  const int wm = wave >> 1, wn = wave & 1, quad = lane >> 4, l16 = lane & 15;
#pragma unroll
  for (int mi = 0; mi < 2; ++mi)
#pragma unroll
    for (int ni = 0; ni < 2; ++ni) {
      int col = bn * 64 + wn * 32 + ni * 16 + l16;
      float bv = biasn[col];
#pragma unroll
      for (int r = 0; r < 4; ++r) {
        int row = bm * 64 + wm * 32 + mi * 16 + quad * 4 + r;
        float v = acc[mi][ni][r] + bv;
        float nv = tanhf_(v);
        size_t idx = (size_t)row * H + col;
        float z = zbuf[idx];
        float hp = hf[idx];
        float hn = (1.0f - z) * nv + z * hp;
        hf[idx] = hn;
        hb[idx] = f2b(hn);
        out[(size_t)row * 3584 + out_off + col] += mask[row * 128 + t] * hn;
      }
    }
}

__global__ void cast_kernel(const float* __restrict__ src,
                            unsigned short* __restrict__ dst, int n) {
  int i = blockIdx.x * 256 + threadIdx.x;
  if (i < n) dst[i] = f2b(src[i]);
}

extern "C" void kernel_launch(void* const* d_in, const int* in_sizes, int n_in,
                              void* d_out, int out_size, void* d_ws,
                              size_t ws_size, hipStream_t stream) {
  const int B = 128, T = 128, I = 512;
  const int Hs[3] = {512, 1024, 2048};
  const int outoff[3] = {0, 512, 1536};

  const float* x = (const float*)d_in[0];
  const float* mask = (const float*)d_in[1];
  const float* Wih[3] = {(const float*)d_in[2], (const float*)d_in[5],
                         (const float*)d_in[8]};
  const float* Whh[3] = {(const float*)d_in[3], (const float*)d_in[6],
                         (const float*)d_in[9]};
  const float* bias[3] = {(const float*)d_in[4], (const float*)d_in[7],
                          (const float*)d_in[10]};

  char* ws = (char*)d_ws;
  size_t off = 0;
  auto alloc = [&](size_t bytes) -> void* {
    void* p = ws + off;
    off = (off + bytes + 255) & ~(size_t)255;
    return p;
  };

  unsigned short* xb = (unsigned short*)alloc((size_t)B * T * I * 2);
  unsigned short *wihb[3], *whhb[3];
  for (int l = 0; l < 3; ++l) {
    int inl = (l == 0) ? I : Hs[l - 1];
    wihb[l] = (unsigned short*)alloc((size_t)3 * Hs[l] * inl * 2);
  }
  for (int l = 0; l < 3; ++l)
    whhb[l] = (unsigned short*)alloc((size_t)3 * Hs[l] * Hs[l] * 2);
  size_t hstart = off;
  float* hf[3];
  unsigned short* hb[3];
  for (int l = 0; l < 3; ++l) hf[l] = (float*)alloc((size_t)B * Hs[l] * 4);
  for (int l = 0; l < 3; ++l)
    hb[l] = (unsigned short*)alloc((size_t)B * Hs[l] * 2);
  size_t hend = off;
  float* zbuf = (float*)alloc((size_t)B * 2048 * 4);
  unsigned short* rh = (unsigned short*)alloc((size_t)B * 2048 * 2);
  (void)ws_size;

  auto cast = [&](const float* s, unsigned short* d, int n) {
    cast_kernel<<<(n + 255) / 256, 256, 0, stream>>>(s, d, n);
  };
  cast(x, xb, B * T * I);
  for (int l = 0; l < 3; ++l) {
    int inl = (l == 0) ? I : Hs[l - 1];
    cast(Wih[l], wihb[l], 3 * Hs[l] * inl);
    cast(Whh[l], whhb[l], 3 * Hs[l] * Hs[l]);
  }
  hipMemsetAsync(ws + hstart, 0, hend - hstart, stream);
  hipMemsetAsync(d_out, 0, (size_t)out_size * 4, stream);

  for (int t = 0; t < T; ++t) {
    for (int l = 0; l < 3; ++l) {
      int H = Hs[l];
      int inl = (l == 0) ? I : Hs[l - 1];
      const unsigned short* A1 = (l == 0) ? xb + (size_t)t * I : hb[l - 1];
      int ldA1 = (l == 0) ? T * I : inl;

      dim3 gzr(2, (unsigned)(2 * H / 64));
      step_zr_kernel<<<gzr, 256, 0, stream>>>(A1, ldA1, inl, hb[l], H, wihb[l],
                                              whhb[l], bias[l], hf[l], zbuf,
                                              rh, H);
      dim3 gn(2, (unsigned)(H / 64));
      step_n_kernel<<<gn, 256, 0, stream>>>(
          A1, ldA1, inl, rh, H, wihb[l] + (size_t)2 * H * inl,
          whhb[l] + (size_t)2 * H * H, bias[l] + 2 * H, zbuf, hf[l], hb[l],
          (float*)d_out, outoff[l], mask, t, H);
    }
  }
}